// Round 3
// baseline (9932.849 us; speedup 1.0000x reference)
//
#include <hip/hip_runtime.h>
#include <hip/hip_bf16.h>
#include <math.h>

#define M_  4
#define N_  50000
#define E_  400000
#define IN_ 128
#define C_  128
#define HID_ 256

// ---------------------------------------------------------------------------
// Uniform tiled f32 GEMM: 128 rows x 128 cols per block, 256 threads, 8x8
// micro-tile with split-half fragments (conflict-free LDS), double-buffered.
// grid = (ceil(R/128), MB, NC/128)
// AMODE 0: A[b*aBatch + r*K + k]
// AMODE 1: A[b*aBatch + r*K + k] - A2[r*128 + k]    (feat_diff = out1 - xd)
// AMODE 2: A[(k>>7)*strideM + r*128 + (k&127)]      (gate_in view of [M][N][C])
// AMODE 3: A[idx[r]*K + k]                          (gathered rows, MB=1)
// EPI 0: store  1: relu  2: sigmoid
// EPI 4: Cmat[idx[r]*NC + c] += rowscale[idx[r]]*(acc+bias[c])   (MB=1)
// Reff = cnts ? cnts[0] : R
// ---------------------------------------------------------------------------
template<int AMODE, int EPI>
__global__ void __launch_bounds__(256, 4) gemm3(
    const float* A, const float* A2, const float* __restrict__ B,
    const float* __restrict__ bias, float* Cmat,
    const float* __restrict__ rowscale, const int* __restrict__ idx,
    const int* __restrict__ cnts,
    int R, int K, int NC,
    long long aBatch, long long bBatch, int biasBatch, long long cBatch,
    long long strideM)
{
  __shared__ float As[2][8][128];
  __shared__ float Bs[2][8][128];

  const int tid = threadIdx.x;
  const int b = blockIdx.y;
  const int Reff = cnts ? cnts[0] : R;
  const int rb = blockIdx.x * 128;
  if (rb >= Reff) return;
  const int cb = blockIdx.z * 128;

  const float* Ab = (AMODE == 2) ? A : (A + (long long)b * aBatch);
  const float* Bb = B + (long long)b * bBatch + cb;
  const float* biasb = bias + (long long)b * biasBatch + cb;

  // A loader: 128 rows x 8 k, one float4 per thread
  const int ar = tid >> 1;
  const int ak = (tid & 1) * 4;
  const int r_a = rb + ar;
  const bool a_ok = (r_a < Reff);
  long long a_row = 0;
  if (a_ok) {
    if (AMODE == 3)      a_row = (long long)idx[r_a] * K;
    else if (AMODE == 2) a_row = (long long)r_a * 128;
    else                 a_row = (long long)r_a * K;
  }
  // B loader: 8 k x 128 cols, one float4 per thread
  const int bk = tid >> 5;
  const int bc = (tid & 31) * 4;

  const int tx = tid & 15;
  const int ty = tid >> 4;

  float acc[8][8];
  #pragma unroll
  for (int i = 0; i < 8; ++i)
    #pragma unroll
    for (int j = 0; j < 8; ++j) acc[i][j] = 0.f;

  const int nt = K >> 3;

  // prologue: load tile 0
  float4 av = make_float4(0.f, 0.f, 0.f, 0.f), bv;
  if (a_ok) {
    if (AMODE == 2) {
      av = *(const float4*)(Ab + (long long)(ak >> 7) * strideM + a_row + (ak & 127));
    } else {
      av = *(const float4*)(Ab + a_row + ak);
      if (AMODE == 1) {
        float4 y = *(const float4*)(A2 + (long long)r_a * 128 + ak);
        av.x -= y.x; av.y -= y.y; av.z -= y.z; av.w -= y.w;
      }
    }
  }
  bv = *(const float4*)(Bb + (long long)bk * NC + bc);
  As[0][ak + 0][ar] = av.x; As[0][ak + 1][ar] = av.y;
  As[0][ak + 2][ar] = av.z; As[0][ak + 3][ar] = av.w;
  *(float4*)(&Bs[0][bk][bc]) = bv;
  __syncthreads();

  for (int t = 0; t < nt; ++t) {
    const int cur = t & 1;
    float4 nav = make_float4(0.f, 0.f, 0.f, 0.f), nbv;
    const bool more = (t + 1 < nt);
    if (more) {
      const int k0 = (t + 1) * 8;
      if (a_ok) {
        if (AMODE == 2) {
          int kk0 = k0 + ak;
          nav = *(const float4*)(Ab + (long long)(kk0 >> 7) * strideM + a_row + (kk0 & 127));
        } else {
          nav = *(const float4*)(Ab + a_row + k0 + ak);
          if (AMODE == 1) {
            float4 y = *(const float4*)(A2 + (long long)r_a * 128 + k0 + ak);
            nav.x -= y.x; nav.y -= y.y; nav.z -= y.z; nav.w -= y.w;
          }
        }
      }
      nbv = *(const float4*)(Bb + (long long)(k0 + bk) * NC + bc);
    }

    #pragma unroll
    for (int kk = 0; kk < 8; ++kk) {
      float4 alo = *(float4*)(&As[cur][kk][ty * 4]);
      float4 ahi = *(float4*)(&As[cur][kk][64 + ty * 4]);
      float4 blo = *(float4*)(&Bs[cur][kk][tx * 4]);
      float4 bhi = *(float4*)(&Bs[cur][kk][64 + tx * 4]);
      float a8[8] = {alo.x, alo.y, alo.z, alo.w, ahi.x, ahi.y, ahi.z, ahi.w};
      float b8[8] = {blo.x, blo.y, blo.z, blo.w, bhi.x, bhi.y, bhi.z, bhi.w};
      #pragma unroll
      for (int i = 0; i < 8; ++i)
        #pragma unroll
        for (int j = 0; j < 8; ++j)
          acc[i][j] += a8[i] * b8[j];
    }

    if (more) {
      __syncthreads();   // everyone done reading buf cur^1 (from iter t-1)
      const int nxt = cur ^ 1;
      As[nxt][ak + 0][ar] = nav.x; As[nxt][ak + 1][ar] = nav.y;
      As[nxt][ak + 2][ar] = nav.z; As[nxt][ak + 3][ar] = nav.w;
      *(float4*)(&Bs[nxt][bk][bc]) = nbv;
      __syncthreads();   // writes visible before next compute
    }
  }

  #pragma unroll
  for (int i = 0; i < 8; ++i) {
    const int r = rb + (i < 4 ? ty * 4 + i : 64 + ty * 4 + (i - 4));
    if (r >= Reff) continue;
    long long crow;
    float w = 0.f;
    if (EPI == 4) {
      int orow = idx[r];
      w = rowscale[orow];
      crow = (long long)orow * NC + cb;
    } else {
      crow = (long long)b * cBatch + (long long)r * NC + cb;
    }
    #pragma unroll
    for (int j = 0; j < 8; ++j) {
      const int c = (j < 4 ? tx * 4 + j : 64 + tx * 4 + (j - 4));
      float v = acc[i][j] + biasb[c];
      if (EPI == 1) v = fmaxf(v, 0.f);
      if (EPI == 2) v = 1.f / (1.f + expf(-v));
      if (EPI == 4) Cmat[crow + c] += w * v;
      else          Cmat[crow + c] = v;
    }
  }
}

// a[m*Nn + n] = dot(X[row(n)], lin[m*128 ..]) ; perM: row = m*Nn+n else n
__global__ void attn_logit_kernel(const float* __restrict__ X, const float* __restrict__ lin,
                                  float* __restrict__ out, int Nn, int perM)
{
  int m = blockIdx.y;
  int w = blockIdx.x * (blockDim.x >> 6) + (threadIdx.x >> 6);
  int lane = threadIdx.x & 63;
  if (w >= Nn) return;
  long long row = perM ? ((long long)m * Nn + w) : (long long)w;
  const float* xr = X + row * 128;
  const float* lr = lin + m * 128;
  float acc = xr[lane] * lr[lane] + xr[lane + 64] * lr[lane + 64];
  #pragma unroll
  for (int off = 32; off > 0; off >>= 1) acc += __shfl_down(acc, off);
  if (lane == 0) out[(long long)m * Nn + w] = acc;
}

// ---- CSR build ----
__global__ void count_kernel(const int* __restrict__ dst, int* __restrict__ cnt, int Nn)
{
  int e = blockIdx.x * blockDim.x + threadIdx.x;
  int m = blockIdx.y;
  if (e >= E_) return;
  atomicAdd(&cnt[(long long)m * Nn + dst[(long long)m * E_ + e]], 1);
}

__global__ void scan_kernel(const int* __restrict__ cnt, int* __restrict__ rowptr, int Nn)
{
  __shared__ int sd[1024];
  int m = blockIdx.x;
  int tid = threadIdx.x;
  const int* c = cnt + (long long)m * Nn;
  int* rp = rowptr + (long long)m * (Nn + 1);
  if (tid == 0) rp[0] = 0;
  int running = 0;
  for (int base = 0; base < Nn; base += 1024) {
    int i = base + tid;
    int v = (i < Nn) ? c[i] : 0;
    sd[tid] = v;
    __syncthreads();
    for (int off = 1; off < 1024; off <<= 1) {
      int t = (tid >= off) ? sd[tid - off] : 0;
      __syncthreads();
      sd[tid] += t;
      __syncthreads();
    }
    if (i < Nn) rp[i + 1] = running + sd[tid];
    int tot = sd[1023];
    __syncthreads();
    running += tot;
  }
}

__global__ void scatter_kernel(const int* __restrict__ dst, const int* __restrict__ rowptr,
                               int* __restrict__ fill, int* __restrict__ col, int Nn)
{
  int e = blockIdx.x * blockDim.x + threadIdx.x;
  int m = blockIdx.y;
  if (e >= E_) return;
  int d = dst[(long long)m * E_ + e];
  int pos = rowptr[(long long)m * (Nn + 1) + d] + atomicAdd(&fill[(long long)m * Nn + d], 1);
  col[(long long)m * E_ + pos] = e;
}

__global__ void sortbucket_kernel(const int* __restrict__ rowptr, int* __restrict__ col, int Nn)
{
  int n = blockIdx.x * blockDim.x + threadIdx.x;
  int m = blockIdx.y;
  if (n >= Nn) return;
  const int* rp = rowptr + (long long)m * (Nn + 1);
  int* c = col + (long long)m * E_;
  int b = rp[n], e = rp[n + 1];
  for (int i = b + 1; i < e; ++i) {
    int v = c[i]; int j = i - 1;
    while (j >= b && c[j] > v) { c[j + 1] = c[j]; --j; }
    c[j + 1] = v;
  }
}

// fused GAT propagation, batched over m (pass 1 only; recept factors out)
__global__ void prop_kernel(const float* __restrict__ xs, const float* __restrict__ asrc,
                            const float* __restrict__ adst, const int* __restrict__ rowptr,
                            const int* __restrict__ col, const int* __restrict__ src,
                            float* __restrict__ out)
{
  int d = blockIdx.x;
  int m = blockIdx.y;
  int c = threadIdx.x;   // 128
  const int* rp = rowptr + (long long)m * (N_ + 1);
  const int* cl = col + (long long)m * E_;
  const int* sr = src + (long long)m * E_;
  const float* as_ = asrc + (long long)m * N_;
  const float* xsm = xs + (long long)m * N_ * 128;
  int b = rp[d], en = rp[d + 1];
  long long obase = ((long long)m * N_ + d) * 128 + c;
  if (b == en) { out[obase] = 0.f; return; }
  float ad = adst[(long long)m * N_ + d];
  float emax = -INFINITY;
  for (int j = b; j < en; ++j) {
    int s = sr[cl[j]];
    float e = as_[s] + ad;
    e = (e >= 0.f) ? e : 0.2f * e;
    emax = fmaxf(emax, e);
  }
  float den = 0.f, acc = 0.f;
  for (int j = b; j < en; ++j) {
    int s = sr[cl[j]];
    float e = as_[s] + ad;
    e = (e >= 0.f) ? e : 0.2f * e;
    float ez = expf(e - emax);
    den += ez;
    acc += ez * xsm[(long long)s * 128 + c];
  }
  out[obase] = acc / (den + 1e-16f);
}

// gd = mean_c(mo * (out1 - xd)); recept = gd/(|gd|+1e-8)   (batched over m)
__global__ void gd_kernel(const float* __restrict__ mo, const float* __restrict__ out1,
                          const float* __restrict__ xd, float* __restrict__ recept)
{
  int n = blockIdx.x;
  int m = blockIdx.y;
  int c = threadIdx.x;  // 128
  long long idx = ((long long)m * N_ + n) * 128 + c;
  float fd = out1[idx] - xd[(long long)n * 128 + c];
  float v = mo[idx] * fd;
  __shared__ float red[128];
  red[c] = v;
  __syncthreads();
  for (int off = 64; off > 0; off >>= 1) {
    if (c < off) red[c] += red[c + off];
    __syncthreads();
  }
  if (c == 0) {
    float gd = red[0] / 128.f;
    recept[(long long)m * N_ + n] = gd / (fabsf(gd) + 1e-8f);
  }
}

// feats = relu(recept[m,n] * out1), in place; float4 over [M,N,C]
__global__ void scale_relu_kernel(float* __restrict__ buf, const float* __restrict__ recept)
{
  long long i4 = ((long long)blockIdx.x * blockDim.x + threadIdx.x) * 4;
  if (i4 >= (long long)M_ * N_ * 128) return;
  long long node = i4 >> 7;            // m*N + n
  float r = recept[node];
  float4 v = *(float4*)(buf + i4);
  v.x = fmaxf(v.x * r, 0.f);
  v.y = fmaxf(v.y * r, 0.f);
  v.z = fmaxf(v.z * r, 0.f);
  v.w = fmaxf(v.w * r, 0.f);
  *(float4*)(buf + i4) = v;
}

// logits[n, 0..3] = h[n,0..255] @ W2[256,4] + b2
__global__ void gate_logits_kernel(const float* __restrict__ h, const float* __restrict__ W2,
                                   const float* __restrict__ b2, float* __restrict__ logits, int Nn)
{
  int w = blockIdx.x * (blockDim.x >> 6) + (threadIdx.x >> 6);
  int lane = threadIdx.x & 63;
  if (w >= Nn) return;
  const float* hr = h + (long long)w * 256;
  float a0 = 0.f, a1 = 0.f, a2 = 0.f, a3 = 0.f;
  for (int j = lane; j < 256; j += 64) {
    float hv = hr[j];
    a0 += hv * W2[j * 4 + 0];
    a1 += hv * W2[j * 4 + 1];
    a2 += hv * W2[j * 4 + 2];
    a3 += hv * W2[j * 4 + 3];
  }
  #pragma unroll
  for (int off = 32; off > 0; off >>= 1) {
    a0 += __shfl_down(a0, off);
    a1 += __shfl_down(a1, off);
    a2 += __shfl_down(a2, off);
    a3 += __shfl_down(a3, off);
  }
  if (lane == 0) {
    long long o = (long long)w * 4;
    logits[o + 0] = a0 + b2[0];
    logits[o + 1] = a1 + b2[1];
    logits[o + 2] = a2 + b2[2];
    logits[o + 3] = a3 + b2[3];
  }
}

// softmax + recept.T + top-2 (ties: lower index) -> wsel[M,N]
__global__ void topk_kernel(const float* __restrict__ logits, const float* __restrict__ recept,
                            float* __restrict__ wsel, int Nn)
{
  int n = blockIdx.x * blockDim.x + threadIdx.x;
  if (n >= Nn) return;
  float l[4];
  #pragma unroll
  for (int m = 0; m < 4; ++m) l[m] = logits[(long long)n * 4 + m];
  float mx = fmaxf(fmaxf(l[0], l[1]), fmaxf(l[2], l[3]));
  float e[4], s = 0.f;
  #pragma unroll
  for (int m = 0; m < 4; ++m) { e[m] = expf(l[m] - mx); s += e[m]; }
  float sc[4];
  #pragma unroll
  for (int m = 0; m < 4; ++m) sc[m] = e[m] / s + recept[(long long)m * Nn + n];
  int i0 = 0; float v0 = sc[0];
  #pragma unroll
  for (int m = 1; m < 4; ++m) if (sc[m] > v0) { v0 = sc[m]; i0 = m; }
  int i1 = -1; float v1 = -INFINITY;
  #pragma unroll
  for (int m = 0; m < 4; ++m) { if (m == i0) continue; if (sc[m] > v1) { v1 = sc[m]; i1 = m; } }
  float ts = v0 + v1;
  float w0 = v0 / ts, w1 = v1 / ts;
  #pragma unroll
  for (int m = 0; m < 4; ++m)
    wsel[(long long)m * Nn + n] = (m == i0) ? w0 : ((m == i1) ? w1 : 0.f);
}

__global__ void compact_kernel(const float* __restrict__ wsel, int* __restrict__ idx,
                               int* __restrict__ cnts, int Nn)
{
  int n = blockIdx.x * blockDim.x + threadIdx.x;
  if (n >= Nn) return;
  #pragma unroll
  for (int m = 0; m < 4; ++m) {
    if (wsel[(long long)m * Nn + n] != 0.f) {
      int p = atomicAdd(&cnts[m], 1);
      idx[(long long)m * Nn + p] = n;
    }
  }
}

extern "C" void kernel_launch(void* const* d_in, const int* in_sizes, int n_in,
                              void* d_out, int out_size, void* d_ws, size_t ws_size,
                              hipStream_t stream) {
  const float* x_src   = (const float*)d_in[0];
  const float* x_dst   = (const float*)d_in[1];
  const int*   src_idx = (const int*)d_in[2];
  const int*   dst_idx = (const int*)d_in[3];
  const float* proj_Ws = (const float*)d_in[4];
  const float* proj_bs = (const float*)d_in[5];
  const float* projd_W = (const float*)d_in[6];
  const float* projd_b = (const float*)d_in[7];
  const float* lin_src = (const float*)d_in[8];
  const float* lin_dst = (const float*)d_in[9];
  const float* gm_W1   = (const float*)d_in[10];
  const float* gm_b1   = (const float*)d_in[11];
  const float* gm_W2   = (const float*)d_in[12];
  const float* gm_b2   = (const float*)d_in[13];
  const float* gate_W1 = (const float*)d_in[14];
  const float* gate_b1 = (const float*)d_in[15];
  const float* gate_W2 = (const float*)d_in[16];
  const float* gate_b2 = (const float*)d_in[17];
  const float* exp_W1  = (const float*)d_in[18];
  const float* exp_b1  = (const float*)d_in[19];
  const float* exp_W2  = (const float*)d_in[20];
  const float* exp_b2  = (const float*)d_in[21];
  float* final_out = (float*)d_out;

  float* ws = (float*)d_ws;
  float* bufA   = ws;                        // [M,N,128]: xs -> h1/mo -> gate-h -> expert-h
  float* bufB   = ws + 25600000LL;           // [M,N,128]: out1 -> feats (in-place)
  float* xd     = ws + 51200000LL;           // [N,128]
  float* asrc   = ws + 57600000LL;           // [M,N]
  float* adst   = ws + 57800000LL;           // [M,N]
  float* recept = ws + 58000000LL;           // [M,N]
  float* wsel   = ws + 58200000LL;           // [M,N]
  float* logits = ws + 58400000LL;           // [N,4]
  int*   ibase  = (int*)(ws + 58600000LL);
  int*   rowptr = ibase;                     // [M,(N+1)]
  int*   col    = ibase + 200004;            // [M,E]
  int*   cnt    = ibase + 1800004;           // [M,N]
  int*   expidx = cnt;                       // reuse after CSR build
  int*   expcnt = ibase + 2000004;           // [4]

  const long long NC = (long long)N_ * C_;
  const int RB = (N_ + 127) / 128;           // 391

  hipMemsetAsync(d_out, 0, (size_t)out_size * sizeof(float), stream);

  // ---- CSR build ----
  hipMemsetAsync(cnt, 0, (size_t)M_ * N_ * sizeof(int), stream);
  count_kernel<<<dim3((E_ + 255) / 256, M_), 256, 0, stream>>>(dst_idx, cnt, N_);
  scan_kernel<<<M_, 1024, 0, stream>>>(cnt, rowptr, N_);
  hipMemsetAsync(cnt, 0, (size_t)M_ * N_ * sizeof(int), stream);
  scatter_kernel<<<dim3((E_ + 255) / 256, M_), 256, 0, stream>>>(dst_idx, rowptr, cnt, col, N_);
  sortbucket_kernel<<<dim3((N_ + 255) / 256, M_), 256, 0, stream>>>(rowptr, col, N_);

  // ---- xd = x_dst @ projd_W + b ----
  gemm3<0, 0><<<dim3(RB, 1, 1), 256, 0, stream>>>(
      x_dst, nullptr, projd_W, projd_b, xd, nullptr, nullptr, nullptr,
      N_, IN_, C_, 0, 0, 0, 0, 0);
  attn_logit_kernel<<<dim3((N_ + 3) / 4, M_), 256, 0, stream>>>(xd, lin_dst, adst, N_, 0);

  // ---- xs = per-type projection (batched over m) ----
  gemm3<0, 0><<<dim3(RB, M_, 1), 256, 0, stream>>>(
      x_src, nullptr, proj_Ws, proj_bs, bufA, nullptr, nullptr, nullptr,
      N_, IN_, C_, NC, (long long)IN_ * C_, C_, NC, 0);
  attn_logit_kernel<<<dim3((N_ + 3) / 4, M_), 256, 0, stream>>>(bufA, lin_src, asrc, N_, 1);

  // ---- propagation pass 1 (batched) -> out1 in bufB ----
  prop_kernel<<<dim3(N_, M_), 128, 0, stream>>>(bufA, asrc, adst, rowptr, col, src_idx, bufB);

  // ---- grad-map MLP (batched): h1 = relu(fd@W1+b1); mo = sigmoid(h1@W2+b2) ----
  gemm3<1, 1><<<dim3(RB, M_, 1), 256, 0, stream>>>(
      bufB, xd, gm_W1, gm_b1, bufA, nullptr, nullptr, nullptr,
      N_, C_, C_, NC, 0, 0, NC, 0);
  gemm3<0, 2><<<dim3(RB, M_, 1), 256, 0, stream>>>(
      bufA, nullptr, gm_W2, gm_b2, bufA, nullptr, nullptr, nullptr,
      N_, C_, C_, NC, 0, 0, NC, 0);
  gd_kernel<<<dim3(N_, M_), 128, 0, stream>>>(bufA, bufB, xd, recept);

  // ---- pass 2 == recept * out1 (algebraic identity), + relu -> feats in bufB ----
  scale_relu_kernel<<<(int)(((long long)M_ * N_ * 128 / 4 + 255) / 256), 256, 0, stream>>>(
      bufB, recept);

  // ---- gate: h = relu(gate_in @ W1 + b1), gate_in = [M,N,C] view, K=512 ----
  gemm3<2, 1><<<dim3(RB, 1, 2), 256, 0, stream>>>(
      bufB, nullptr, gate_W1, gate_b1, bufA, nullptr, nullptr, nullptr,
      N_, M_ * C_, HID_, 0, 0, 0, 0, NC);
  gate_logits_kernel<<<dim3((N_ + 3) / 4), 256, 0, stream>>>(bufA, gate_W2, gate_b2, logits, N_);
  topk_kernel<<<(N_ + 255) / 256, 256, 0, stream>>>(logits, recept, wsel, N_);

  // ---- top-2 compaction ----
  hipMemsetAsync(expcnt, 0, 4 * sizeof(int), stream);
  compact_kernel<<<(N_ + 255) / 256, 256, 0, stream>>>(wsel, expidx, expcnt, N_);

  // ---- experts (compacted rows, weighted scatter-accumulate into final) ----
  for (int m = 0; m < M_; ++m) {
    gemm3<3, 1><<<dim3(RB, 1, 2), 256, 0, stream>>>(
        bufB + m * NC, nullptr, exp_W1 + (long long)m * C_ * HID_,
        exp_b1 + (long long)m * HID_, bufA, nullptr,
        expidx + (long long)m * N_, expcnt + m,
        N_, C_, HID_, 0, 0, 0, 0, 0);
    gemm3<0, 4><<<dim3(RB, 1, 1), 256, 0, stream>>>(
        bufA, nullptr, exp_W2 + (long long)m * HID_ * C_,
        exp_b2 + (long long)m * C_, final_out, wsel + (long long)m * N_,
        expidx + (long long)m * N_, expcnt + m,
        N_, HID_, C_, 0, 0, 0, 0, 0);
  }
}

// Round 4
// 1731.689 us; speedup vs baseline: 5.7359x; 5.7359x over previous
//
#include <hip/hip_runtime.h>
#include <hip/hip_bf16.h>
#include <math.h>

#define M_  4
#define N_  50000
#define E_  400000
#define IN_ 128
#define C_  128
#define HID_ 256

// ---------------------------------------------------------------------------
// Uniform tiled f32 GEMM: 128 rows x 128 cols per block, 256 threads, 8x8
// micro-tile, split-half fragments (bandwidth-minimal LDS), SINGLE-buffered.
// NOTE: no min-occupancy in __launch_bounds__ — (256,4) capped VGPR at 64 and
// spilled the 64-entry accumulator to scratch (10 GB HBM traffic, R3).
// grid = (ceil(R/128), MB, NC/128)
// AMODE 0: A[b*aBatch + r*K + k]
// AMODE 1: A[b*aBatch + r*K + k] - A2[r*128 + k]    (feat_diff = out1 - xd)
// AMODE 2: A[(k>>7)*strideM + r*128 + (k&127)]      (gate_in view of [M][N][C])
// AMODE 3: A[idx[r]*K + k]                          (gathered rows, MB=1)
// EPI 0: store  1: relu  2: sigmoid
// EPI 4: Cmat[idx[r]*NC + c] += rowscale[idx[r]]*(acc+bias[c])   (MB=1)
// Reff = cnts ? cnts[0] : R
// ---------------------------------------------------------------------------
template<int AMODE, int EPI>
__global__ void __launch_bounds__(256) gemm4(
    const float* A, const float* A2, const float* __restrict__ B,
    const float* __restrict__ bias, float* Cmat,
    const float* __restrict__ rowscale, const int* __restrict__ idx,
    const int* __restrict__ cnts,
    int R, int K, int NC,
    long long aBatch, long long bBatch, int biasBatch, long long cBatch,
    long long strideM)
{
  __shared__ float As[8][128];
  __shared__ float Bs[8][128];

  const int tid = threadIdx.x;
  const int b = blockIdx.y;
  const int Reff = cnts ? cnts[0] : R;
  const int rb = blockIdx.x * 128;
  if (rb >= Reff) return;
  const int cb = blockIdx.z * 128;

  const float* Ab = (AMODE == 2) ? A : (A + (long long)b * aBatch);
  const float* Bb = B + (long long)b * bBatch + cb;
  const float* biasb = bias + (long long)b * biasBatch + cb;

  // A loader: 128 rows x 8 k, one float4 per thread
  const int ar = tid >> 1;
  const int ak = (tid & 1) * 4;
  const int r_a = rb + ar;
  const bool a_ok = (r_a < Reff);
  long long a_row = 0;
  if (a_ok) {
    if (AMODE == 3)      a_row = (long long)idx[r_a] * K;
    else if (AMODE == 2) a_row = (long long)r_a * 128;
    else                 a_row = (long long)r_a * K;
  }
  // B loader: 8 k x 128 cols, one float4 per thread
  const int bk = tid >> 5;
  const int bc = (tid & 31) * 4;

  const int tx = tid & 15;
  const int ty = tid >> 4;

  float acc[8][8];
  #pragma unroll
  for (int i = 0; i < 8; ++i)
    #pragma unroll
    for (int j = 0; j < 8; ++j) acc[i][j] = 0.f;

  for (int k0 = 0; k0 < K; k0 += 8) {
    float4 av = make_float4(0.f, 0.f, 0.f, 0.f), bv;
    if (a_ok) {
      if (AMODE == 2) {
        int kk0 = k0 + ak;
        av = *(const float4*)(Ab + (long long)(kk0 >> 7) * strideM + a_row + (kk0 & 127));
      } else {
        av = *(const float4*)(Ab + a_row + k0 + ak);
        if (AMODE == 1) {
          float4 y = *(const float4*)(A2 + (long long)r_a * 128 + k0 + ak);
          av.x -= y.x; av.y -= y.y; av.z -= y.z; av.w -= y.w;
        }
      }
    }
    bv = *(const float4*)(Bb + (long long)(k0 + bk) * NC + bc);

    __syncthreads();   // previous tile's readers done
    As[ak + 0][ar] = av.x; As[ak + 1][ar] = av.y;
    As[ak + 2][ar] = av.z; As[ak + 3][ar] = av.w;
    *(float4*)(&Bs[bk][bc]) = bv;
    __syncthreads();   // writes visible

    #pragma unroll
    for (int kk = 0; kk < 8; ++kk) {
      float4 alo = *(float4*)(&As[kk][ty * 4]);
      float4 ahi = *(float4*)(&As[kk][64 + ty * 4]);
      float4 blo = *(float4*)(&Bs[kk][tx * 4]);
      float4 bhi = *(float4*)(&Bs[kk][64 + tx * 4]);
      float a8[8] = {alo.x, alo.y, alo.z, alo.w, ahi.x, ahi.y, ahi.z, ahi.w};
      float b8[8] = {blo.x, blo.y, blo.z, blo.w, bhi.x, bhi.y, bhi.z, bhi.w};
      #pragma unroll
      for (int i = 0; i < 8; ++i)
        #pragma unroll
        for (int j = 0; j < 8; ++j)
          acc[i][j] += a8[i] * b8[j];
    }
  }

  #pragma unroll
  for (int i = 0; i < 8; ++i) {
    const int r = rb + (i < 4 ? ty * 4 + i : 64 + ty * 4 + (i - 4));
    if (r >= Reff) continue;
    long long crow;
    float w = 0.f;
    if (EPI == 4) {
      int orow = idx[r];
      w = rowscale[orow];
      crow = (long long)orow * NC + cb;
    } else {
      crow = (long long)b * cBatch + (long long)r * NC + cb;
    }
    #pragma unroll
    for (int j = 0; j < 8; ++j) {
      const int c = (j < 4 ? tx * 4 + j : 64 + tx * 4 + (j - 4));
      float v = acc[i][j] + biasb[c];
      if (EPI == 1) v = fmaxf(v, 0.f);
      if (EPI == 2) v = 1.f / (1.f + expf(-v));
      if (EPI == 4) Cmat[crow + c] += w * v;
      else          Cmat[crow + c] = v;
    }
  }
}

// a[m*Nn + n] = dot(X[row(n)], lin[m*128 ..]) ; perM: row = m*Nn+n else n
__global__ void attn_logit_kernel(const float* __restrict__ X, const float* __restrict__ lin,
                                  float* __restrict__ out, int Nn, int perM)
{
  int m = blockIdx.y;
  int w = blockIdx.x * (blockDim.x >> 6) + (threadIdx.x >> 6);
  int lane = threadIdx.x & 63;
  if (w >= Nn) return;
  long long row = perM ? ((long long)m * Nn + w) : (long long)w;
  const float* xr = X + row * 128;
  const float* lr = lin + m * 128;
  float acc = xr[lane] * lr[lane] + xr[lane + 64] * lr[lane + 64];
  #pragma unroll
  for (int off = 32; off > 0; off >>= 1) acc += __shfl_down(acc, off);
  if (lane == 0) out[(long long)m * Nn + w] = acc;
}

// ---- CSR build ----
__global__ void count_kernel(const int* __restrict__ dst, int* __restrict__ cnt, int Nn)
{
  int e = blockIdx.x * blockDim.x + threadIdx.x;
  int m = blockIdx.y;
  if (e >= E_) return;
  atomicAdd(&cnt[(long long)m * Nn + dst[(long long)m * E_ + e]], 1);
}

__global__ void scan_kernel(const int* __restrict__ cnt, int* __restrict__ rowptr, int Nn)
{
  __shared__ int sd[1024];
  int m = blockIdx.x;
  int tid = threadIdx.x;
  const int* c = cnt + (long long)m * Nn;
  int* rp = rowptr + (long long)m * (Nn + 1);
  if (tid == 0) rp[0] = 0;
  int running = 0;
  for (int base = 0; base < Nn; base += 1024) {
    int i = base + tid;
    int v = (i < Nn) ? c[i] : 0;
    sd[tid] = v;
    __syncthreads();
    for (int off = 1; off < 1024; off <<= 1) {
      int t = (tid >= off) ? sd[tid - off] : 0;
      __syncthreads();
      sd[tid] += t;
      __syncthreads();
    }
    if (i < Nn) rp[i + 1] = running + sd[tid];
    int tot = sd[1023];
    __syncthreads();
    running += tot;
  }
}

__global__ void scatter_kernel(const int* __restrict__ dst, const int* __restrict__ rowptr,
                               int* __restrict__ fill, int* __restrict__ col, int Nn)
{
  int e = blockIdx.x * blockDim.x + threadIdx.x;
  int m = blockIdx.y;
  if (e >= E_) return;
  int d = dst[(long long)m * E_ + e];
  int pos = rowptr[(long long)m * (Nn + 1) + d] + atomicAdd(&fill[(long long)m * Nn + d], 1);
  col[(long long)m * E_ + pos] = e;
}

__global__ void sortbucket_kernel(const int* __restrict__ rowptr, int* __restrict__ col, int Nn)
{
  int n = blockIdx.x * blockDim.x + threadIdx.x;
  int m = blockIdx.y;
  if (n >= Nn) return;
  const int* rp = rowptr + (long long)m * (Nn + 1);
  int* c = col + (long long)m * E_;
  int b = rp[n], e = rp[n + 1];
  for (int i = b + 1; i < e; ++i) {
    int v = c[i]; int j = i - 1;
    while (j >= b && c[j] > v) { c[j + 1] = c[j]; --j; }
    c[j + 1] = v;
  }
}

// fused GAT propagation, batched over m (pass 1 only; recept factors out)
__global__ void prop_kernel(const float* __restrict__ xs, const float* __restrict__ asrc,
                            const float* __restrict__ adst, const int* __restrict__ rowptr,
                            const int* __restrict__ col, const int* __restrict__ src,
                            float* __restrict__ out)
{
  int d = blockIdx.x;
  int m = blockIdx.y;
  int c = threadIdx.x;   // 128
  const int* rp = rowptr + (long long)m * (N_ + 1);
  const int* cl = col + (long long)m * E_;
  const int* sr = src + (long long)m * E_;
  const float* as_ = asrc + (long long)m * N_;
  const float* xsm = xs + (long long)m * N_ * 128;
  int b = rp[d], en = rp[d + 1];
  long long obase = ((long long)m * N_ + d) * 128 + c;
  if (b == en) { out[obase] = 0.f; return; }
  float ad = adst[(long long)m * N_ + d];
  float emax = -INFINITY;
  for (int j = b; j < en; ++j) {
    int s = sr[cl[j]];
    float e = as_[s] + ad;
    e = (e >= 0.f) ? e : 0.2f * e;
    emax = fmaxf(emax, e);
  }
  float den = 0.f, acc = 0.f;
  for (int j = b; j < en; ++j) {
    int s = sr[cl[j]];
    float e = as_[s] + ad;
    e = (e >= 0.f) ? e : 0.2f * e;
    float ez = expf(e - emax);
    den += ez;
    acc += ez * xsm[(long long)s * 128 + c];
  }
  out[obase] = acc / (den + 1e-16f);
}

// gd = mean_c(mo * (out1 - xd)); recept = gd/(|gd|+1e-8)   (batched over m)
__global__ void gd_kernel(const float* __restrict__ mo, const float* __restrict__ out1,
                          const float* __restrict__ xd, float* __restrict__ recept)
{
  int n = blockIdx.x;
  int m = blockIdx.y;
  int c = threadIdx.x;  // 128
  long long idx = ((long long)m * N_ + n) * 128 + c;
  float fd = out1[idx] - xd[(long long)n * 128 + c];
  float v = mo[idx] * fd;
  __shared__ float red[128];
  red[c] = v;
  __syncthreads();
  for (int off = 64; off > 0; off >>= 1) {
    if (c < off) red[c] += red[c + off];
    __syncthreads();
  }
  if (c == 0) {
    float gd = red[0] / 128.f;
    recept[(long long)m * N_ + n] = gd / (fabsf(gd) + 1e-8f);
  }
}

// feats = relu(recept[m,n] * out1), in place; float4 over [M,N,C]
__global__ void scale_relu_kernel(float* __restrict__ buf, const float* __restrict__ recept)
{
  long long i4 = ((long long)blockIdx.x * blockDim.x + threadIdx.x) * 4;
  if (i4 >= (long long)M_ * N_ * 128) return;
  long long node = i4 >> 7;            // m*N + n
  float r = recept[node];
  float4 v = *(float4*)(buf + i4);
  v.x = fmaxf(v.x * r, 0.f);
  v.y = fmaxf(v.y * r, 0.f);
  v.z = fmaxf(v.z * r, 0.f);
  v.w = fmaxf(v.w * r, 0.f);
  *(float4*)(buf + i4) = v;
}

// logits[n, 0..3] = h[n,0..255] @ W2[256,4] + b2
__global__ void gate_logits_kernel(const float* __restrict__ h, const float* __restrict__ W2,
                                   const float* __restrict__ b2, float* __restrict__ logits, int Nn)
{
  int w = blockIdx.x * (blockDim.x >> 6) + (threadIdx.x >> 6);
  int lane = threadIdx.x & 63;
  if (w >= Nn) return;
  const float* hr = h + (long long)w * 256;
  float a0 = 0.f, a1 = 0.f, a2 = 0.f, a3 = 0.f;
  for (int j = lane; j < 256; j += 64) {
    float hv = hr[j];
    a0 += hv * W2[j * 4 + 0];
    a1 += hv * W2[j * 4 + 1];
    a2 += hv * W2[j * 4 + 2];
    a3 += hv * W2[j * 4 + 3];
  }
  #pragma unroll
  for (int off = 32; off > 0; off >>= 1) {
    a0 += __shfl_down(a0, off);
    a1 += __shfl_down(a1, off);
    a2 += __shfl_down(a2, off);
    a3 += __shfl_down(a3, off);
  }
  if (lane == 0) {
    long long o = (long long)w * 4;
    logits[o + 0] = a0 + b2[0];
    logits[o + 1] = a1 + b2[1];
    logits[o + 2] = a2 + b2[2];
    logits[o + 3] = a3 + b2[3];
  }
}

// softmax + recept.T + top-2 (ties: lower index) -> wsel[M,N]
__global__ void topk_kernel(const float* __restrict__ logits, const float* __restrict__ recept,
                            float* __restrict__ wsel, int Nn)
{
  int n = blockIdx.x * blockDim.x + threadIdx.x;
  if (n >= Nn) return;
  float l[4];
  #pragma unroll
  for (int m = 0; m < 4; ++m) l[m] = logits[(long long)n * 4 + m];
  float mx = fmaxf(fmaxf(l[0], l[1]), fmaxf(l[2], l[3]));
  float e[4], s = 0.f;
  #pragma unroll
  for (int m = 0; m < 4; ++m) { e[m] = expf(l[m] - mx); s += e[m]; }
  float sc[4];
  #pragma unroll
  for (int m = 0; m < 4; ++m) sc[m] = e[m] / s + recept[(long long)m * Nn + n];
  int i0 = 0; float v0 = sc[0];
  #pragma unroll
  for (int m = 1; m < 4; ++m) if (sc[m] > v0) { v0 = sc[m]; i0 = m; }
  int i1 = -1; float v1 = -INFINITY;
  #pragma unroll
  for (int m = 0; m < 4; ++m) { if (m == i0) continue; if (sc[m] > v1) { v1 = sc[m]; i1 = m; } }
  float ts = v0 + v1;
  float w0 = v0 / ts, w1 = v1 / ts;
  #pragma unroll
  for (int m = 0; m < 4; ++m)
    wsel[(long long)m * Nn + n] = (m == i0) ? w0 : ((m == i1) ? w1 : 0.f);
}

__global__ void compact_kernel(const float* __restrict__ wsel, int* __restrict__ idx,
                               int* __restrict__ cnts, int Nn)
{
  int n = blockIdx.x * blockDim.x + threadIdx.x;
  if (n >= Nn) return;
  #pragma unroll
  for (int m = 0; m < 4; ++m) {
    if (wsel[(long long)m * Nn + n] != 0.f) {
      int p = atomicAdd(&cnts[m], 1);
      idx[(long long)m * Nn + p] = n;
    }
  }
}

extern "C" void kernel_launch(void* const* d_in, const int* in_sizes, int n_in,
                              void* d_out, int out_size, void* d_ws, size_t ws_size,
                              hipStream_t stream) {
  const float* x_src   = (const float*)d_in[0];
  const float* x_dst   = (const float*)d_in[1];
  const int*   src_idx = (const int*)d_in[2];
  const int*   dst_idx = (const int*)d_in[3];
  const float* proj_Ws = (const float*)d_in[4];
  const float* proj_bs = (const float*)d_in[5];
  const float* projd_W = (const float*)d_in[6];
  const float* projd_b = (const float*)d_in[7];
  const float* lin_src = (const float*)d_in[8];
  const float* lin_dst = (const float*)d_in[9];
  const float* gm_W1   = (const float*)d_in[10];
  const float* gm_b1   = (const float*)d_in[11];
  const float* gm_W2   = (const float*)d_in[12];
  const float* gm_b2   = (const float*)d_in[13];
  const float* gate_W1 = (const float*)d_in[14];
  const float* gate_b1 = (const float*)d_in[15];
  const float* gate_W2 = (const float*)d_in[16];
  const float* gate_b2 = (const float*)d_in[17];
  const float* exp_W1  = (const float*)d_in[18];
  const float* exp_b1  = (const float*)d_in[19];
  const float* exp_W2  = (const float*)d_in[20];
  const float* exp_b2  = (const float*)d_in[21];
  float* final_out = (float*)d_out;

  float* ws = (float*)d_ws;
  float* bufA   = ws;                        // [M,N,128]: xs -> h1/mo -> gate-h -> expert-h
  float* bufB   = ws + 25600000LL;           // [M,N,128]: out1 -> feats (in-place)
  float* xd     = ws + 51200000LL;           // [N,128]
  float* asrc   = ws + 57600000LL;           // [M,N]
  float* adst   = ws + 57800000LL;           // [M,N]
  float* recept = ws + 58000000LL;           // [M,N]
  float* wsel   = ws + 58200000LL;           // [M,N]
  float* logits = ws + 58400000LL;           // [N,4]
  int*   ibase  = (int*)(ws + 58600000LL);
  int*   rowptr = ibase;                     // [M,(N+1)]
  int*   col    = ibase + 200004;            // [M,E]
  int*   cnt    = ibase + 1800004;           // [M,N]
  int*   expidx = cnt;                       // reuse after CSR build
  int*   expcnt = ibase + 2000004;           // [4]

  const long long NC = (long long)N_ * C_;
  const int RB = (N_ + 127) / 128;           // 391

  hipMemsetAsync(d_out, 0, (size_t)out_size * sizeof(float), stream);

  // ---- CSR build ----
  hipMemsetAsync(cnt, 0, (size_t)M_ * N_ * sizeof(int), stream);
  count_kernel<<<dim3((E_ + 255) / 256, M_), 256, 0, stream>>>(dst_idx, cnt, N_);
  scan_kernel<<<M_, 1024, 0, stream>>>(cnt, rowptr, N_);
  hipMemsetAsync(cnt, 0, (size_t)M_ * N_ * sizeof(int), stream);
  scatter_kernel<<<dim3((E_ + 255) / 256, M_), 256, 0, stream>>>(dst_idx, rowptr, cnt, col, N_);
  sortbucket_kernel<<<dim3((N_ + 255) / 256, M_), 256, 0, stream>>>(rowptr, col, N_);

  // ---- xd = x_dst @ projd_W + b ----
  gemm4<0, 0><<<dim3(RB, 1, 1), 256, 0, stream>>>(
      x_dst, nullptr, projd_W, projd_b, xd, nullptr, nullptr, nullptr,
      N_, IN_, C_, 0, 0, 0, 0, 0);
  attn_logit_kernel<<<dim3((N_ + 3) / 4, M_), 256, 0, stream>>>(xd, lin_dst, adst, N_, 0);

  // ---- xs = per-type projection (batched over m) ----
  gemm4<0, 0><<<dim3(RB, M_, 1), 256, 0, stream>>>(
      x_src, nullptr, proj_Ws, proj_bs, bufA, nullptr, nullptr, nullptr,
      N_, IN_, C_, NC, (long long)IN_ * C_, C_, NC, 0);
  attn_logit_kernel<<<dim3((N_ + 3) / 4, M_), 256, 0, stream>>>(bufA, lin_src, asrc, N_, 1);

  // ---- propagation pass 1 (batched) -> out1 in bufB ----
  prop_kernel<<<dim3(N_, M_), 128, 0, stream>>>(bufA, asrc, adst, rowptr, col, src_idx, bufB);

  // ---- grad-map MLP (batched): h1 = relu(fd@W1+b1); mo = sigmoid(h1@W2+b2) ----
  gemm4<1, 1><<<dim3(RB, M_, 1), 256, 0, stream>>>(
      bufB, xd, gm_W1, gm_b1, bufA, nullptr, nullptr, nullptr,
      N_, C_, C_, NC, 0, 0, NC, 0);
  gemm4<0, 2><<<dim3(RB, M_, 1), 256, 0, stream>>>(
      bufA, nullptr, gm_W2, gm_b2, bufA, nullptr, nullptr, nullptr,
      N_, C_, C_, NC, 0, 0, NC, 0);
  gd_kernel<<<dim3(N_, M_), 128, 0, stream>>>(bufA, bufB, xd, recept);

  // ---- pass 2 == recept * out1 (algebraic identity), + relu -> feats in bufB ----
  scale_relu_kernel<<<(int)(((long long)M_ * N_ * 128 / 4 + 255) / 256), 256, 0, stream>>>(
      bufB, recept);

  // ---- gate: h = relu(gate_in @ W1 + b1), gate_in = [M,N,C] view, K=512 ----
  gemm4<2, 1><<<dim3(RB, 1, 2), 256, 0, stream>>>(
      bufB, nullptr, gate_W1, gate_b1, bufA, nullptr, nullptr, nullptr,
      N_, M_ * C_, HID_, 0, 0, 0, 0, NC);
  gate_logits_kernel<<<dim3((N_ + 3) / 4), 256, 0, stream>>>(bufA, gate_W2, gate_b2, logits, N_);
  topk_kernel<<<(N_ + 255) / 256, 256, 0, stream>>>(logits, recept, wsel, N_);

  // ---- top-2 compaction ----
  hipMemsetAsync(expcnt, 0, 4 * sizeof(int), stream);
  compact_kernel<<<(N_ + 255) / 256, 256, 0, stream>>>(wsel, expidx, expcnt, N_);

  // ---- experts (compacted rows, weighted scatter-accumulate into final) ----
  for (int m = 0; m < M_; ++m) {
    gemm4<3, 1><<<dim3(RB, 1, 2), 256, 0, stream>>>(
        bufB + m * NC, nullptr, exp_W1 + (long long)m * C_ * HID_,
        exp_b1 + (long long)m * HID_, bufA, nullptr,
        expidx + (long long)m * N_, expcnt + m,
        N_, C_, HID_, 0, 0, 0, 0, 0);
    gemm4<0, 4><<<dim3(RB, 1, 1), 256, 0, stream>>>(
        bufA, nullptr, exp_W2 + (long long)m * HID_ * C_,
        exp_b2 + (long long)m * C_, final_out, wsel + (long long)m * N_,
        expidx + (long long)m * N_, expcnt + m,
        N_, HID_, C_, 0, 0, 0, 0, 0);
  }
}

// Round 5
// 1543.998 us; speedup vs baseline: 6.4332x; 1.1216x over previous
//
#include <hip/hip_runtime.h>
#include <hip/hip_bf16.h>
#include <math.h>

#define M_  4
#define N_  50000
#define E_  400000
#define IN_ 128
#define C_  128
#define HID_ 256

// ---------------------------------------------------------------------------
// Uniform tiled f32 GEMM: 128 rows x 128 cols per block, 256 threads, 8x8
// micro-tile, split-half fragments, single-buffered LDS.
// (NO min-occupancy launch_bounds: (256,4) capped VGPRs at 64 and spilled the
//  accumulator to scratch -> 10 GB HBM traffic, R3.)
// grid = (ceil(R/128), MB, NC/128)
// AMODE 0: A[b*aBatch + r*K + k]
// AMODE 1: A[b*aBatch + r*K + k] - A2[r*128 + k]    (feat_diff = out1 - xd)
// AMODE 2: A[(k>>7)*strideM + r*128 + (k&127)]      (gate_in view of [M][N][C])
// AMODE 3: A[idx[r]*K + k]                          (gathered rows, MB=1)
// ASCALE 0: none
// ASCALE 1: a = relu(AS[(k>>7)*N_ + r] * a)         (fused feats for AMODE 2)
// ASCALE 2: a = relu(AS[idx[r]] * a)                (fused feats for AMODE 3)
// EPI 0: store  1: relu  2: sigmoid
// EPI 4: Cmat[idx[r]*NC + c] += rowscale[idx[r]]*(acc+bias[c])   (MB=1)
// Reff = cnts ? cnts[0] : R
// ---------------------------------------------------------------------------
template<int AMODE, int EPI, int ASCALE>
__global__ void __launch_bounds__(256) gemm5(
    const float* A, const float* A2, const float* __restrict__ B,
    const float* __restrict__ bias, float* Cmat,
    const float* __restrict__ rowscale, const int* __restrict__ idx,
    const int* __restrict__ cnts, const float* __restrict__ AS,
    int R, int K, int NC,
    long long aBatch, long long bBatch, int biasBatch, long long cBatch,
    long long strideM)
{
  __shared__ float As[8][128];
  __shared__ float Bs[8][128];

  const int tid = threadIdx.x;
  const int b = blockIdx.y;
  const int Reff = cnts ? cnts[0] : R;
  const int rb = blockIdx.x * 128;
  if (rb >= Reff) return;
  const int cb = blockIdx.z * 128;

  const float* Ab = (AMODE == 2) ? A : (A + (long long)b * aBatch);
  const float* Bb = B + (long long)b * bBatch + cb;
  const float* biasb = bias + (long long)b * biasBatch + cb;

  // A loader: 128 rows x 8 k, one float4 per thread
  const int ar = tid >> 1;
  const int ak = (tid & 1) * 4;
  const int r_a = rb + ar;
  const bool a_ok = (r_a < Reff);
  long long a_row = 0;
  float a_rs = 0.f;
  if (a_ok) {
    if (AMODE == 3) {
      int orow = idx[r_a];
      a_row = (long long)orow * K;
      if (ASCALE == 2) a_rs = AS[orow];
    }
    else if (AMODE == 2) a_row = (long long)r_a * 128;
    else                 a_row = (long long)r_a * K;
  }
  // B loader: 8 k x 128 cols, one float4 per thread
  const int bk = tid >> 5;
  const int bc = (tid & 31) * 4;

  const int tx = tid & 15;
  const int ty = tid >> 4;

  float acc[8][8];
  #pragma unroll
  for (int i = 0; i < 8; ++i)
    #pragma unroll
    for (int j = 0; j < 8; ++j) acc[i][j] = 0.f;

  for (int k0 = 0; k0 < K; k0 += 8) {
    float4 av = make_float4(0.f, 0.f, 0.f, 0.f), bv;
    if (a_ok) {
      if (AMODE == 2) {
        int kk0 = k0 + ak;
        av = *(const float4*)(Ab + (long long)(kk0 >> 7) * strideM + a_row + (kk0 & 127));
        if (ASCALE == 1) {
          float rs = AS[(kk0 >> 7) * N_ + r_a];
          av.x = fmaxf(av.x * rs, 0.f); av.y = fmaxf(av.y * rs, 0.f);
          av.z = fmaxf(av.z * rs, 0.f); av.w = fmaxf(av.w * rs, 0.f);
        }
      } else {
        av = *(const float4*)(Ab + a_row + k0 + ak);
        if (AMODE == 1) {
          float4 y = *(const float4*)(A2 + (long long)r_a * 128 + k0 + ak);
          av.x -= y.x; av.y -= y.y; av.z -= y.z; av.w -= y.w;
        }
        if (AMODE == 3 && ASCALE == 2) {
          av.x = fmaxf(av.x * a_rs, 0.f); av.y = fmaxf(av.y * a_rs, 0.f);
          av.z = fmaxf(av.z * a_rs, 0.f); av.w = fmaxf(av.w * a_rs, 0.f);
        }
      }
    }
    bv = *(const float4*)(Bb + (long long)(k0 + bk) * NC + bc);

    __syncthreads();   // previous tile's readers done
    As[ak + 0][ar] = av.x; As[ak + 1][ar] = av.y;
    As[ak + 2][ar] = av.z; As[ak + 3][ar] = av.w;
    *(float4*)(&Bs[bk][bc]) = bv;
    __syncthreads();   // writes visible

    #pragma unroll
    for (int kk = 0; kk < 8; ++kk) {
      float4 alo = *(float4*)(&As[kk][ty * 4]);
      float4 ahi = *(float4*)(&As[kk][64 + ty * 4]);
      float4 blo = *(float4*)(&Bs[kk][tx * 4]);
      float4 bhi = *(float4*)(&Bs[kk][64 + tx * 4]);
      float a8[8] = {alo.x, alo.y, alo.z, alo.w, ahi.x, ahi.y, ahi.z, ahi.w};
      float b8[8] = {blo.x, blo.y, blo.z, blo.w, bhi.x, bhi.y, bhi.z, bhi.w};
      #pragma unroll
      for (int i = 0; i < 8; ++i)
        #pragma unroll
        for (int j = 0; j < 8; ++j)
          acc[i][j] += a8[i] * b8[j];
    }
  }

  #pragma unroll
  for (int i = 0; i < 8; ++i) {
    const int r = rb + (i < 4 ? ty * 4 + i : 64 + ty * 4 + (i - 4));
    if (r >= Reff) continue;
    long long crow;
    float w = 0.f;
    if (EPI == 4) {
      int orow = idx[r];
      w = rowscale[orow];
      crow = (long long)orow * NC + cb;
    } else {
      crow = (long long)b * cBatch + (long long)r * NC + cb;
    }
    #pragma unroll
    for (int j = 0; j < 8; ++j) {
      const int c = (j < 4 ? tx * 4 + j : 64 + tx * 4 + (j - 4));
      float v = acc[i][j] + biasb[c];
      if (EPI == 1) v = fmaxf(v, 0.f);
      if (EPI == 2) v = 1.f / (1.f + expf(-v));
      if (EPI == 4) Cmat[crow + c] += w * v;
      else          Cmat[crow + c] = v;
    }
  }
}

// a[m*Nn + n] = dot(X[row(n)], lin[m*128 ..]) ; perM: row = m*Nn+n else n
__global__ void attn_logit_kernel(const float* __restrict__ X, const float* __restrict__ lin,
                                  float* __restrict__ out, int Nn, int perM)
{
  int m = blockIdx.y;
  int w = blockIdx.x * (blockDim.x >> 6) + (threadIdx.x >> 6);
  int lane = threadIdx.x & 63;
  if (w >= Nn) return;
  long long row = perM ? ((long long)m * Nn + w) : (long long)w;
  const float* xr = X + row * 128;
  const float* lr = lin + m * 128;
  float acc = xr[lane] * lr[lane] + xr[lane + 64] * lr[lane + 64];
  #pragma unroll
  for (int off = 32; off > 0; off >>= 1) acc += __shfl_down(acc, off);
  if (lane == 0) out[(long long)m * Nn + w] = acc;
}

// ---- CSR build ----
__global__ void count_kernel(const int* __restrict__ dst, int* __restrict__ cnt, int Nn)
{
  int e = blockIdx.x * blockDim.x + threadIdx.x;
  int m = blockIdx.y;
  if (e >= E_) return;
  atomicAdd(&cnt[(long long)m * Nn + dst[(long long)m * E_ + e]], 1);
}

__global__ void scan_kernel(const int* __restrict__ cnt, int* __restrict__ rowptr, int Nn)
{
  __shared__ int sd[1024];
  int m = blockIdx.x;
  int tid = threadIdx.x;
  const int* c = cnt + (long long)m * Nn;
  int* rp = rowptr + (long long)m * (Nn + 1);
  if (tid == 0) rp[0] = 0;
  int running = 0;
  for (int base = 0; base < Nn; base += 1024) {
    int i = base + tid;
    int v = (i < Nn) ? c[i] : 0;
    sd[tid] = v;
    __syncthreads();
    for (int off = 1; off < 1024; off <<= 1) {
      int t = (tid >= off) ? sd[tid - off] : 0;
      __syncthreads();
      sd[tid] += t;
      __syncthreads();
    }
    if (i < Nn) rp[i + 1] = running + sd[tid];
    int tot = sd[1023];
    __syncthreads();
    running += tot;
  }
}

__global__ void scatter_kernel(const int* __restrict__ dst, const int* __restrict__ rowptr,
                               int* __restrict__ fill, int* __restrict__ col, int Nn)
{
  int e = blockIdx.x * blockDim.x + threadIdx.x;
  int m = blockIdx.y;
  if (e >= E_) return;
  int d = dst[(long long)m * E_ + e];
  int pos = rowptr[(long long)m * (Nn + 1) + d] + atomicAdd(&fill[(long long)m * Nn + d], 1);
  col[(long long)m * E_ + pos] = e;
}

__global__ void sortbucket_kernel(const int* __restrict__ rowptr, int* __restrict__ col, int Nn)
{
  int n = blockIdx.x * blockDim.x + threadIdx.x;
  int m = blockIdx.y;
  if (n >= Nn) return;
  const int* rp = rowptr + (long long)m * (Nn + 1);
  int* c = col + (long long)m * E_;
  int b = rp[n], e = rp[n + 1];
  for (int i = b + 1; i < e; ++i) {
    int v = c[i]; int j = i - 1;
    while (j >= b && c[j] > v) { c[j + 1] = c[j]; --j; }
    c[j + 1] = v;
  }
}

// per-edge attention logit, edge-parallel (coalesced index reads, 4B gathers)
__global__ void edge_e_kernel(const int* __restrict__ src, const int* __restrict__ dst,
                              const float* __restrict__ asrc, const float* __restrict__ adst,
                              float* __restrict__ e_edge)
{
  int e = blockIdx.x * blockDim.x + threadIdx.x;
  int m = blockIdx.y;
  if (e >= E_) return;
  long long off = (long long)m * E_ + e;
  float v = asrc[(long long)m * N_ + src[off]] + adst[(long long)m * N_ + dst[off]];
  e_edge[off] = (v >= 0.f) ? v : 0.2f * v;
}

// per-node softmax over its bucket -> alpha + src id in CSR order
__global__ void alpha_kernel(const int* __restrict__ rowptr, const int* __restrict__ col,
                             const int* __restrict__ src, const float* __restrict__ e_edge,
                             float* __restrict__ alpha, int* __restrict__ src_csr)
{
  int n = blockIdx.x * blockDim.x + threadIdx.x;
  int m = blockIdx.y;
  if (n >= N_) return;
  const int* rp = rowptr + (long long)m * (N_ + 1);
  const int* cl = col + (long long)m * E_;
  const int* sr = src + (long long)m * E_;
  const float* ee = e_edge + (long long)m * E_;
  float* al = alpha + (long long)m * E_;
  int* sc = src_csr + (long long)m * E_;
  int b = rp[n], en = rp[n + 1];
  if (b == en) return;
  float emax = -INFINITY;
  for (int j = b; j < en; ++j) emax = fmaxf(emax, ee[cl[j]]);
  float den = 0.f;
  for (int j = b; j < en; ++j) {
    int eid = cl[j];
    float ez = expf(ee[eid] - emax);
    den += ez;
    al[j] = ez;
    sc[j] = sr[eid];
  }
  float inv = 1.f / (den + 1e-16f);
  for (int j = b; j < en; ++j) al[j] *= inv;
}

// heavy gather: out1[d] = sum_j alpha[j] * xs[src_csr[j]]; single pass, 4 in flight
__global__ void prop2_kernel(const float* __restrict__ xs, const int* __restrict__ rowptr,
                             const float* __restrict__ alpha, const int* __restrict__ src_csr,
                             float* __restrict__ out)
{
  int d = blockIdx.x;
  int m = blockIdx.y;
  int c = threadIdx.x;   // 128
  const int* rp = rowptr + (long long)m * (N_ + 1);
  const float* al = alpha + (long long)m * E_;
  const int* sc = src_csr + (long long)m * E_;
  const float* xsm = xs + (long long)m * N_ * 128;
  int b = rp[d], en = rp[d + 1];
  float acc = 0.f;
  int j = b;
  for (; j + 3 < en; j += 4) {
    float a0 = al[j], a1 = al[j + 1], a2 = al[j + 2], a3 = al[j + 3];
    int s0 = sc[j], s1 = sc[j + 1], s2 = sc[j + 2], s3 = sc[j + 3];
    float x0 = xsm[(long long)s0 * 128 + c];
    float x1 = xsm[(long long)s1 * 128 + c];
    float x2 = xsm[(long long)s2 * 128 + c];
    float x3 = xsm[(long long)s3 * 128 + c];
    acc += a0 * x0; acc += a1 * x1; acc += a2 * x2; acc += a3 * x3;
  }
  for (; j < en; ++j)
    acc += al[j] * xsm[(long long)sc[j] * 128 + c];
  out[((long long)m * N_ + d) * 128 + c] = acc;
}

// gd = mean_c(mo * (out1 - xd)); recept = gd/(|gd|+1e-8)   (batched over m)
__global__ void gd_kernel(const float* __restrict__ mo, const float* __restrict__ out1,
                          const float* __restrict__ xd, float* __restrict__ recept)
{
  int n = blockIdx.x;
  int m = blockIdx.y;
  int c = threadIdx.x;  // 128
  long long idx = ((long long)m * N_ + n) * 128 + c;
  float fd = out1[idx] - xd[(long long)n * 128 + c];
  float v = mo[idx] * fd;
  __shared__ float red[128];
  red[c] = v;
  __syncthreads();
  for (int off = 64; off > 0; off >>= 1) {
    if (c < off) red[c] += red[c + off];
    __syncthreads();
  }
  if (c == 0) {
    float gd = red[0] / 128.f;
    recept[(long long)m * N_ + n] = gd / (fabsf(gd) + 1e-8f);
  }
}

// logits[n, 0..3] = h[n,0..255] @ W2[256,4] + b2
__global__ void gate_logits_kernel(const float* __restrict__ h, const float* __restrict__ W2,
                                   const float* __restrict__ b2, float* __restrict__ logits, int Nn)
{
  int w = blockIdx.x * (blockDim.x >> 6) + (threadIdx.x >> 6);
  int lane = threadIdx.x & 63;
  if (w >= Nn) return;
  const float* hr = h + (long long)w * 256;
  float a0 = 0.f, a1 = 0.f, a2 = 0.f, a3 = 0.f;
  for (int j = lane; j < 256; j += 64) {
    float hv = hr[j];
    a0 += hv * W2[j * 4 + 0];
    a1 += hv * W2[j * 4 + 1];
    a2 += hv * W2[j * 4 + 2];
    a3 += hv * W2[j * 4 + 3];
  }
  #pragma unroll
  for (int off = 32; off > 0; off >>= 1) {
    a0 += __shfl_down(a0, off);
    a1 += __shfl_down(a1, off);
    a2 += __shfl_down(a2, off);
    a3 += __shfl_down(a3, off);
  }
  if (lane == 0) {
    long long o = (long long)w * 4;
    logits[o + 0] = a0 + b2[0];
    logits[o + 1] = a1 + b2[1];
    logits[o + 2] = a2 + b2[2];
    logits[o + 3] = a3 + b2[3];
  }
}

// softmax + recept.T + top-2 (ties: lower index) -> wsel[M,N]
__global__ void topk_kernel(const float* __restrict__ logits, const float* __restrict__ recept,
                            float* __restrict__ wsel, int Nn)
{
  int n = blockIdx.x * blockDim.x + threadIdx.x;
  if (n >= Nn) return;
  float l[4];
  #pragma unroll
  for (int m = 0; m < 4; ++m) l[m] = logits[(long long)n * 4 + m];
  float mx = fmaxf(fmaxf(l[0], l[1]), fmaxf(l[2], l[3]));
  float e[4], s = 0.f;
  #pragma unroll
  for (int m = 0; m < 4; ++m) { e[m] = expf(l[m] - mx); s += e[m]; }
  float sc[4];
  #pragma unroll
  for (int m = 0; m < 4; ++m) sc[m] = e[m] / s + recept[(long long)m * Nn + n];
  int i0 = 0; float v0 = sc[0];
  #pragma unroll
  for (int m = 1; m < 4; ++m) if (sc[m] > v0) { v0 = sc[m]; i0 = m; }
  int i1 = -1; float v1 = -INFINITY;
  #pragma unroll
  for (int m = 0; m < 4; ++m) { if (m == i0) continue; if (sc[m] > v1) { v1 = sc[m]; i1 = m; } }
  float ts = v0 + v1;
  float w0 = v0 / ts, w1 = v1 / ts;
  #pragma unroll
  for (int m = 0; m < 4; ++m)
    wsel[(long long)m * Nn + n] = (m == i0) ? w0 : ((m == i1) ? w1 : 0.f);
}

__global__ void compact_kernel(const float* __restrict__ wsel, int* __restrict__ idx,
                               int* __restrict__ cnts, int Nn)
{
  int n = blockIdx.x * blockDim.x + threadIdx.x;
  if (n >= Nn) return;
  #pragma unroll
  for (int m = 0; m < 4; ++m) {
    if (wsel[(long long)m * Nn + n] != 0.f) {
      int p = atomicAdd(&cnts[m], 1);
      idx[(long long)m * Nn + p] = n;
    }
  }
}

extern "C" void kernel_launch(void* const* d_in, const int* in_sizes, int n_in,
                              void* d_out, int out_size, void* d_ws, size_t ws_size,
                              hipStream_t stream) {
  const float* x_src   = (const float*)d_in[0];
  const float* x_dst   = (const float*)d_in[1];
  const int*   src_idx = (const int*)d_in[2];
  const int*   dst_idx = (const int*)d_in[3];
  const float* proj_Ws = (const float*)d_in[4];
  const float* proj_bs = (const float*)d_in[5];
  const float* projd_W = (const float*)d_in[6];
  const float* projd_b = (const float*)d_in[7];
  const float* lin_src = (const float*)d_in[8];
  const float* lin_dst = (const float*)d_in[9];
  const float* gm_W1   = (const float*)d_in[10];
  const float* gm_b1   = (const float*)d_in[11];
  const float* gm_W2   = (const float*)d_in[12];
  const float* gm_b2   = (const float*)d_in[13];
  const float* gate_W1 = (const float*)d_in[14];
  const float* gate_b1 = (const float*)d_in[15];
  const float* gate_W2 = (const float*)d_in[16];
  const float* gate_b2 = (const float*)d_in[17];
  const float* exp_W1  = (const float*)d_in[18];
  const float* exp_b1  = (const float*)d_in[19];
  const float* exp_W2  = (const float*)d_in[20];
  const float* exp_b2  = (const float*)d_in[21];
  float* final_out = (float*)d_out;

  float* ws = (float*)d_ws;
  float* bufA   = ws;                        // [M,N,128]: xs -> h1/mo -> gate-h -> expert-h
  float* bufB   = ws + 25600000LL;           // [M,N,128]: out1 (never overwritten by feats)
  float* xd     = ws + 51200000LL;           // [N,128]
  float* asrc   = ws + 57600000LL;           // [M,N]
  float* adst   = ws + 57800000LL;           // [M,N]
  float* recept = ws + 58000000LL;           // [M,N]
  float* wsel   = ws + 58200000LL;           // [M,N]
  float* logits = ws + 58400000LL;           // [N,4]
  float* e_edge = ws + 58600000LL;           // [M,E]
  float* alpha  = ws + 60200000LL;           // [M,E]
  int*   ibase  = (int*)(ws + 61800000LL);
  int*   rowptr = ibase;                     // [M,(N+1)]
  int*   col    = ibase + 200004;            // [M,E]
  int*   cnt    = ibase + 1800004;           // [M,N]
  int*   expidx = cnt;                       // reuse after CSR build
  int*   expcnt = ibase + 2000004;           // [4]
  int*   src_csr= ibase + 2000008;           // [M,E]

  const long long NC = (long long)N_ * C_;
  const int RB = (N_ + 127) / 128;           // 391

  hipMemsetAsync(d_out, 0, (size_t)out_size * sizeof(float), stream);

  // ---- CSR build ----
  hipMemsetAsync(cnt, 0, (size_t)M_ * N_ * sizeof(int), stream);
  count_kernel<<<dim3((E_ + 255) / 256, M_), 256, 0, stream>>>(dst_idx, cnt, N_);
  scan_kernel<<<M_, 1024, 0, stream>>>(cnt, rowptr, N_);
  hipMemsetAsync(cnt, 0, (size_t)M_ * N_ * sizeof(int), stream);
  scatter_kernel<<<dim3((E_ + 255) / 256, M_), 256, 0, stream>>>(dst_idx, rowptr, cnt, col, N_);
  sortbucket_kernel<<<dim3((N_ + 255) / 256, M_), 256, 0, stream>>>(rowptr, col, N_);

  // ---- xd = x_dst @ projd_W + b ----
  gemm5<0, 0, 0><<<dim3(RB, 1, 1), 256, 0, stream>>>(
      x_dst, nullptr, projd_W, projd_b, xd, nullptr, nullptr, nullptr, nullptr,
      N_, IN_, C_, 0, 0, 0, 0, 0);
  attn_logit_kernel<<<dim3((N_ + 3) / 4, M_), 256, 0, stream>>>(xd, lin_dst, adst, N_, 0);

  // ---- xs = per-type projection (batched over m) ----
  gemm5<0, 0, 0><<<dim3(RB, M_, 1), 256, 0, stream>>>(
      x_src, nullptr, proj_Ws, proj_bs, bufA, nullptr, nullptr, nullptr, nullptr,
      N_, IN_, C_, NC, (long long)IN_ * C_, C_, NC, 0);
  attn_logit_kernel<<<dim3((N_ + 3) / 4, M_), 256, 0, stream>>>(bufA, lin_src, asrc, N_, 1);

  // ---- attention softmax precompute (edge-parallel + per-node buckets) ----
  edge_e_kernel<<<dim3((E_ + 255) / 256, M_), 256, 0, stream>>>(
      src_idx, dst_idx, asrc, adst, e_edge);
  alpha_kernel<<<dim3((N_ + 255) / 256, M_), 256, 0, stream>>>(
      rowptr, col, src_idx, e_edge, alpha, src_csr);

  // ---- propagation (single gather pass) -> out1 in bufB ----
  prop2_kernel<<<dim3(N_, M_), 128, 0, stream>>>(bufA, rowptr, alpha, src_csr, bufB);

  // ---- grad-map MLP (batched): h1 = relu(fd@W1+b1); mo = sigmoid(h1@W2+b2) ----
  gemm5<1, 1, 0><<<dim3(RB, M_, 1), 256, 0, stream>>>(
      bufB, xd, gm_W1, gm_b1, bufA, nullptr, nullptr, nullptr, nullptr,
      N_, C_, C_, NC, 0, 0, NC, 0);
  gemm5<0, 2, 0><<<dim3(RB, M_, 1), 256, 0, stream>>>(
      bufA, nullptr, gm_W2, gm_b2, bufA, nullptr, nullptr, nullptr, nullptr,
      N_, C_, C_, NC, 0, 0, NC, 0);
  gd_kernel<<<dim3(N_, M_), 128, 0, stream>>>(bufA, bufB, xd, recept);

  // ---- gate: h = relu(gate_in @ W1 + b1); feats fused on A-load ----
  gemm5<2, 1, 1><<<dim3(RB, 1, 2), 256, 0, stream>>>(
      bufB, nullptr, gate_W1, gate_b1, bufA, nullptr, nullptr, nullptr, recept,
      N_, M_ * C_, HID_, 0, 0, 0, 0, NC);
  gate_logits_kernel<<<dim3((N_ + 3) / 4), 256, 0, stream>>>(bufA, gate_W2, gate_b2, logits, N_);
  topk_kernel<<<(N_ + 255) / 256, 256, 0, stream>>>(logits, recept, wsel, N_);

  // ---- top-2 compaction ----
  hipMemsetAsync(expcnt, 0, 4 * sizeof(int), stream);
  compact_kernel<<<(N_ + 255) / 256, 256, 0, stream>>>(wsel, expidx, expcnt, N_);

  // ---- experts (compacted rows, feats fused on A-load, scatter-accum) ----
  for (int m = 0; m < M_; ++m) {
    gemm5<3, 1, 2><<<dim3(RB, 1, 2), 256, 0, stream>>>(
        bufB + m * NC, nullptr, exp_W1 + (long long)m * C_ * HID_,
        exp_b1 + (long long)m * HID_, bufA, nullptr,
        expidx + (long long)m * N_, expcnt + m, recept + (long long)m * N_,
        N_, C_, HID_, 0, 0, 0, 0, 0);
    gemm5<0, 4, 0><<<dim3(RB, 1, 1), 256, 0, stream>>>(
        bufA, nullptr, exp_W2 + (long long)m * HID_ * C_,
        exp_b2 + (long long)m * C_, final_out, wsel + (long long)m * N_,
        expidx + (long long)m * N_, expcnt + m, nullptr,
        N_, HID_, C_, 0, 0, 0, 0, 0);
  }
}